// Round 8
// baseline (74.053 us; speedup 1.0000x reference)
//
#include <hip/hip_runtime.h>
#include <hip/hip_bf16.h>
#include <math.h>

#define HW 56
#define PPI (HW*HW)          // 3136 pixels per image
#define NB 4
#define C 128
#define NPIX (NB*PPI)        // 12544

typedef __attribute__((ext_vector_type(8))) short short8;
typedef __attribute__((ext_vector_type(4))) float f32x4;

__device__ __forceinline__ short bfbits(float v) {
    __hip_bfloat16 hb = __float2bfloat16(v);
    return *reinterpret_cast<short*>(&hb);
}
__device__ __forceinline__ unsigned packbf(float a, float b) {
    return (unsigned)(unsigned short)bfbits(a) | ((unsigned)(unsigned short)bfbits(b) << 16);
}

// ---------- Kernel 1: weight prep (qkv B-frags + conv B-frags) — unchanged -------------
__global__ __launch_bounds__(256) void prep_kernel(
    const float* __restrict__ cw,
    const float* __restrict__ qw, const float* __restrict__ kw,
    const float* __restrict__ vw,
    __hip_bfloat16* __restrict__ wcf, __hip_bfloat16* __restrict__ wqkv)
{
    int gid = blockIdx.x * 256 + threadIdx.x;
    if (blockIdx.x < 192) {
        int m   = gid >> 14;
        int r   = gid & 16383;
        int col = r >> 7;
        int k   = r & 127;
        const float* W = (m == 0) ? qw : (m == 1) ? kw : vw;
        int kk = k >> 5, hi = (k >> 3) & 3, j = k & 7;
        wqkv[m * 16384 + ((kk * 4 + hi) * 128 + col) * 8 + j] = __float2bfloat16(W[col * 128 + k]);
    } else {
        int idx = gid - 192 * 256;          // 0..4095
        int hi = idx >> 10, cout = (idx >> 3) & 127, j = idx & 7;
        int k  = hi * 8 + j;
        float v = (k < 27) ? cw[cout * 27 + k] : 0.f;
        wcf[(hi * 128 + cout) * 8 + j] = __float2bfloat16(v);
    }
}

// ---------- Kernel 2: fully fused conv3x3s2+relu -> qkv -> 7x7 NAT ---------------------
// One block per 4x4 output tile (784 blocks), 47.4 KB LDS -> 3 blocks/CU.
// Q computed first (qa regs); per halo chunk: conv -> K/V GEMM -> per-chunk QK^T into
// registers (redundant across waves); softmax fully in-register via 16-lane shfl.
#define VPITCH 272   // bytes per vT / attnW row (136 shorts)
#define XPITCH 24    // shorts per x_lds row
#define XCH    504   // 21*24 shorts per channel

__global__ __launch_bounds__(256, 3) void fused_kernel(
    const float* __restrict__ x, const __hip_bfloat16* __restrict__ wcf,
    const float* __restrict__ cb, const __hip_bfloat16* __restrict__ wqkv,
    const float* __restrict__ qb, const float* __restrict__ kb,
    const float* __restrict__ vb, float* __restrict__ out)
{
    __shared__ __align__(16) short vT[128 * 136];      // 34816 B (XOR bits 4-6, pitch 272)
    __shared__ __align__(16) short poolA[16 * 128];    //  4096 B: q_lds, then k_chunk
    __shared__ __align__(16) short f_ch[16 * 128];     //  4096 B
    __shared__ __align__(16) short poolB[16 * 136];    //  4352 B: x_lds, then attnW
    short* q_lds   = poolA;
    short* k_chunk = poolA;
    short* x_lds   = poolB;
    short* attnW   = poolB;

    int t = threadIdx.x, lane = t & 63, wid = t >> 6;
    int r16 = lane & 15, hi = lane >> 4;

    int bx = blockIdx.x;                 // 4 * 196
    int b  = bx / 196;
    int rr = bx % 196;
    int th = rr / 14, tw = rr % 14;
    int ih0 = min(max(th*4 - 3, 0), HW - 10);
    int iw0 = min(max(tw*4 - 3, 0), HW - 10);

    // ---- stage x patch: 3ch x 21x21 f32 -> bf16 LDS, zero-filled at borders ----
    {
        int ihA = 2*ih0 - 1, iwA = 2*iw0 - 1;
        #pragma unroll
        for (int it = 0; it < 6; ++it) {
            int i = t + 256*it;            // 0..1535, 1512 used
            if (i < 1512) {
                int ci = i / XCH, r = i % XCH;
                int row = r / XPITCH, col = r % XPITCH;
                int ih = ihA + row, iw = iwA + col;
                float xv = 0.f;
                if (col < 21 && ih >= 0 && ih < 112 && iw >= 0 && iw < 112)
                    xv = x[((size_t)(b*3 + ci)*112 + ih)*112 + iw];
                x_lds[i] = bfbits(xv);
            }
        }
    }

    // zero vT LOGICAL units 14,15 (n in [112,128) — never written, read by PV)
    for (int i = t; i < 1024; i += 256) {
        int c = i >> 3, j = i & 7;
        int hsw = (c >> 3) & 7;
        int unit = (14 + (j >> 2)) ^ hsw;
        *(unsigned*)((char*)vT + c*VPITCH + (unit << 4) + (j & 3)*4) = 0u;
    }

    // ---- hoisted per-lane constants: im2col offsets, biases, conv B-frags ----
    int cout0 = (wid*2 + 0)*16 + r16;
    int cout1 = (wid*2 + 1)*16 + r16;
    short8 cbw0 = *(const short8*)((const short*)wcf + (hi*128 + cout0)*8);
    short8 cbw1 = *(const short8*)((const short*)wcf + (hi*128 + cout1)*8);
    float cbias0 = cb[cout0], cbias1 = cb[cout1];

    int  offb[8];
    bool vmask[8];
    #pragma unroll
    for (int j = 0; j < 8; ++j) {
        int k = hi*8 + j;
        int ci = k/9, r9 = k%9, kh = r9/3, kw_ = r9%3;
        offb[j]  = ci*XCH + kh*XPITCH + kw_;
        vmask[j] = (k < 27);
    }

    float kvbias[4];
    #pragma unroll
    for (int i = 0; i < 4; ++i) {
        int idx = wid*4 + i, mv = idx >> 3, ct = idx & 7, c = ct*16 + r16;
        kvbias[i] = mv ? vb[c] : kb[c];
    }
    float qbias[2];
    #pragma unroll
    for (int i = 0; i < 2; ++i) qbias[i] = qb[(wid*2 + i)*16 + r16];

    __syncthreads();   // x_lds ready

    // conv for one 16-pixel chunk (lane row r16 -> LOCAL window pixel (hl,wl)) into f_ch
    auto conv_to_fch = [&](int hl, int wl) {
        int pb = hl*(2*XPITCH) + wl*2;
        short8 af;
        #pragma unroll
        for (int j = 0; j < 8; ++j)
            af[j] = vmask[j] ? x_lds[offb[j] + pb] : (short)0;
        #pragma unroll
        for (int ctl = 0; ctl < 2; ++ctl) {
            int cout   = ctl ? cout1  : cout0;
            short8 bw  = ctl ? cbw1   : cbw0;
            float bias = ctl ? cbias1 : cbias0;
            f32x4 acc = {0.f, 0.f, 0.f, 0.f};
            acc = __builtin_amdgcn_mfma_f32_16x16x32_bf16(af, bw, acc, 0, 0, 0);
            int colblk = cout >> 3, inb = (cout & 7)*2;
            #pragma unroll
            for (int rg = 0; rg < 4; ++rg) {
                int px = hi*4 + rg;
                *(short*)((char*)f_ch + px*256 + ((colblk ^ px) << 4) + inb)
                    = bfbits(fmaxf(acc[rg] + bias, 0.f));
            }
        }
    };

    // ---- Q phase: conv + GEMM for the 16 center pixels -> qa registers ----
    short8 qa[4];
    {
        int ph = th*4 + (r16 >> 2), pw = tw*4 + (r16 & 3);
        conv_to_fch(ph - ih0, pw - iw0);
        __syncthreads();

        short8 fa[4];
        #pragma unroll
        for (int kk = 0; kk < 4; ++kk)
            fa[kk] = *(const short8*)((char*)f_ch + r16*256 + (((kk*4 + hi) ^ r16) << 4));

        #pragma unroll
        for (int i = 0; i < 2; ++i) {
            int ct = wid*2 + i;
            const short* wb = (const short*)wqkv + hi*1024 + r16*8 + ct*128;
            f32x4 acc = {0.f, 0.f, 0.f, 0.f};
            acc = __builtin_amdgcn_mfma_f32_16x16x32_bf16(fa[0], *(const short8*)(wb),         acc, 0, 0, 0);
            acc = __builtin_amdgcn_mfma_f32_16x16x32_bf16(fa[1], *(const short8*)(wb +  4096), acc, 0, 0, 0);
            acc = __builtin_amdgcn_mfma_f32_16x16x32_bf16(fa[2], *(const short8*)(wb +  8192), acc, 0, 0, 0);
            acc = __builtin_amdgcn_mfma_f32_16x16x32_bf16(fa[3], *(const short8*)(wb + 12288), acc, 0, 0, 0);
            int c = ct*16 + r16;
            float bb = qbias[i];
            #pragma unroll
            for (int rg = 0; rg < 4; ++rg) {
                int px = hi*4 + rg;
                *(short*)((char*)q_lds + px*256 + (((c >> 3) ^ px) << 4) + (c & 7)*2)
                    = bfbits(acc[rg] + bb);
            }
        }
        __syncthreads();

        #pragma unroll
        for (int kk = 0; kk < 4; ++kk)
            qa[kk] = *(const short8*)((char*)q_lds + r16*256 + (((kk*4 + hi) ^ r16) << 4));
        // qa reads complete before next __syncthreads(); k_chunk aliasing is then safe
    }

    // ---- halo chunks 0..6: conv -> K/V GEMM -> per-chunk QK^T into registers ----
    float l[7][4];
    for (int cc = 0; cc < 7; ++cc) {
        int nc = min(cc*16 + r16, 99);
        conv_to_fch(nc/10, nc%10);
        __syncthreads();                               // f_ch ready; k_chunk free

        short8 fa[4];
        #pragma unroll
        for (int kk = 0; kk < 4; ++kk)
            fa[kk] = *(const short8*)((char*)f_ch + r16*256 + (((kk*4 + hi) ^ r16) << 4));

        #pragma unroll
        for (int i = 0; i < 4; ++i) {
            int idx = wid*4 + i;       // 0..15, wave-uniform
            int mv  = idx >> 3;        // 0 = k, 1 = v
            int ct  = idx & 7;
            const short* wb = (const short*)wqkv + (1+mv)*16384 + hi*1024 + r16*8 + ct*128;
            f32x4 acc = {0.f, 0.f, 0.f, 0.f};
            acc = __builtin_amdgcn_mfma_f32_16x16x32_bf16(fa[0], *(const short8*)(wb),         acc, 0, 0, 0);
            acc = __builtin_amdgcn_mfma_f32_16x16x32_bf16(fa[1], *(const short8*)(wb +  4096), acc, 0, 0, 0);
            acc = __builtin_amdgcn_mfma_f32_16x16x32_bf16(fa[2], *(const short8*)(wb +  8192), acc, 0, 0, 0);
            acc = __builtin_amdgcn_mfma_f32_16x16x32_bf16(fa[3], *(const short8*)(wb + 12288), acc, 0, 0, 0);
            int c = ct*16 + r16;
            float bb = kvbias[i];
            if (mv == 0) {
                int swz = c >> 3;
                #pragma unroll
                for (int rg = 0; rg < 4; ++rg) {
                    int nl = hi*4 + rg;                // n & 15
                    *(short*)((char*)k_chunk + nl*256 + ((swz ^ nl) << 4) + (c & 7)*2)
                        = bfbits(acc[rg] + bb);
                }
            } else {
                int n0 = cc*16 + hi*4;
                unsigned lo  = packbf(acc[0] + bb, acc[1] + bb);
                unsigned hi2 = packbf(acc[2] + bb, acc[3] + bb);
                int hsw = (c >> 3) & 7;
                int off = (2*n0) ^ (hsw << 4);
                *(uint2*)((char*)vT + c*VPITCH + off) = make_uint2(lo, hi2);
            }
        }
        __syncthreads();                               // k_chunk ready

        // QK^T for this chunk: every wave computes the full 16x16 tile (redundant)
        {
            const char* kbase = (const char*)k_chunk + r16*256;
            f32x4 acc = {0.f, 0.f, 0.f, 0.f};
            #pragma unroll
            for (int kk = 0; kk < 4; ++kk) {
                short8 kv = *(const short8*)(kbase + (((kk*4 + hi) ^ r16) << 4));
                acc = __builtin_amdgcn_mfma_f32_16x16x32_bf16(qa[kk], kv, acc, 0, 0, 0);
            }
            #pragma unroll
            for (int rg = 0; rg < 4; ++rg) l[cc][rg] = acc[rg];
        }
    }

    // ---- in-register softmax per px (16-lane shfl reduce), scatter bf16 to attnW ----
    // lane holds logit[px=hi*4+rg][n=cc*16+r16]
    {
        const float scale = 0.08838834764831845f;   // 128^-0.5
        #pragma unroll
        for (int rg = 0; rg < 4; ++rg) {
            int px = hi*4 + rg;
            int h = th*4 + (px >> 2), w = tw*4 + (px & 3);
            int r0 = min(max(h - 3, 0), HW - 7) - ih0;   // window start, local coords
            int c0 = min(max(w - 3, 0), HW - 7) - iw0;
            float lv[7]; bool vn[7];
            float m = -INFINITY;
            #pragma unroll
            for (int cc = 0; cc < 7; ++cc) {
                int n  = cc*16 + r16;
                int nr = n / 10, ncl = n - nr*10;
                vn[cc] = (n < 100) && ((unsigned)(nr - r0) < 7u) && ((unsigned)(ncl - c0) < 7u);
                lv[cc] = l[cc][rg] * scale;
                if (vn[cc]) m = fmaxf(m, lv[cc]);
            }
            #pragma unroll
            for (int d = 1; d < 16; d <<= 1) m = fmaxf(m, __shfl_xor(m, d));
            float e[7]; float s = 0.f;
            #pragma unroll
            for (int cc = 0; cc < 7; ++cc) {
                e[cc] = vn[cc] ? __expf(lv[cc] - m) : 0.f;
                s += e[cc];
            }
            #pragma unroll
            for (int d = 1; d < 16; d <<= 1) s += __shfl_xor(s, d);
            float rs = 1.f / s;
            #pragma unroll
            for (int cc = 0; cc < 7; ++cc) {
                if ((cc & 3) == wid)    // each n-column written by exactly one wave
                    *(short*)((char*)attnW + px*VPITCH + 2*(cc*16 + r16)) = bfbits(e[cc] * rs);
            }
        }
        // zero attnW tail: n in [112,128) (bytes [224,256) per row), read by pa
        for (int i = t; i < 128; i += 256) {
            int row = i >> 3, j = i & 7;
            *(unsigned*)((char*)attnW + row*VPITCH + 224 + j*4) = 0u;
        }
    }
    __syncthreads();

    // ---- PV: out[16][128] = attnW x vT^T ----
    short8 pa[4];
    #pragma unroll
    for (int kk = 0; kk < 4; ++kk)
        pa[kk] = *(const short8*)((char*)attnW + r16*VPITCH + kk*64 + hi*16);

    for (int nt = wid; nt < 8; nt += 4) {
        int c   = nt*16 + r16;
        int hsw = (c >> 3) & 7;
        const char* vrow = (const char*)vT + c*VPITCH;
        f32x4 acc = {0.f, 0.f, 0.f, 0.f};
        #pragma unroll
        for (int kk = 0; kk < 4; ++kk) {
            short8 vbr = *(const short8*)(vrow + ((kk*64 + hi*16) ^ (hsw << 4)));
            acc = __builtin_amdgcn_mfma_f32_16x16x32_bf16(pa[kk], vbr, acc, 0, 0, 0);
        }
        #pragma unroll
        for (int rg = 0; rg < 4; ++rg) {
            int p = hi*4 + rg;
            int h = th*4 + (p >> 2), w = tw*4 + (p & 3);
            out[(((size_t)b*C + c)*HW + h)*HW + w] = acc[rg];
        }
    }
}

extern "C" void kernel_launch(void* const* d_in, const int* in_sizes, int n_in,
                              void* d_out, int out_size, void* d_ws, size_t ws_size,
                              hipStream_t stream) {
    const float* x      = (const float*)d_in[0];
    const float* conv_w = (const float*)d_in[1];
    const float* conv_b = (const float*)d_in[2];
    const float* q_w    = (const float*)d_in[3];
    const float* q_b    = (const float*)d_in[4];
    const float* k_w    = (const float*)d_in[5];
    const float* k_b    = (const float*)d_in[6];
    const float* v_w    = (const float*)d_in[7];
    const float* v_b    = (const float*)d_in[8];
    float* out = (float*)d_out;

    __hip_bfloat16* wqkv = (__hip_bfloat16*)d_ws;        // 3*16384
    __hip_bfloat16* wcf  = wqkv + 3 * 16384;             // 4096

    prep_kernel<<<208, 256, 0, stream>>>(conv_w, q_w, k_w, v_w, wcf, wqkv);
    fused_kernel<<<NB*196, 256, 0, stream>>>(x, wcf, conv_b, wqkv,
                                             q_b, k_b, v_b, out);
}

// Round 9
// 62.519 us; speedup vs baseline: 1.1845x; 1.1845x over previous
//
#include <hip/hip_runtime.h>
#include <hip/hip_bf16.h>
#include <math.h>

#define HW 56
#define PPI (HW*HW)          // 3136 pixels per image
#define NB 4
#define C 128
#define NPIX (NB*PPI)        // 12544

typedef __attribute__((ext_vector_type(8))) short short8;
typedef __attribute__((ext_vector_type(4))) float f32x4;

__device__ __forceinline__ short bfbits(float v) {
    __hip_bfloat16 hb = __float2bfloat16(v);
    return *reinterpret_cast<short*>(&hb);
}
__device__ __forceinline__ unsigned packbf(float a, float b) {
    return (unsigned)(unsigned short)bfbits(a) | ((unsigned)(unsigned short)bfbits(b) << 16);
}

// ---------- Kernel 1: weight prep (qkv B-frags + conv B-frags) — unchanged -------------
__global__ __launch_bounds__(256) void prep_kernel(
    const float* __restrict__ cw,
    const float* __restrict__ qw, const float* __restrict__ kw,
    const float* __restrict__ vw,
    __hip_bfloat16* __restrict__ wcf, __hip_bfloat16* __restrict__ wqkv)
{
    int gid = blockIdx.x * 256 + threadIdx.x;
    if (blockIdx.x < 192) {
        int m   = gid >> 14;
        int r   = gid & 16383;
        int col = r >> 7;
        int k   = r & 127;
        const float* W = (m == 0) ? qw : (m == 1) ? kw : vw;
        int kk = k >> 5, hi = (k >> 3) & 3, j = k & 7;
        wqkv[m * 16384 + ((kk * 4 + hi) * 128 + col) * 8 + j] = __float2bfloat16(W[col * 128 + k]);
    } else {
        int idx = gid - 192 * 256;          // 0..4095
        int hi = idx >> 10, cout = (idx >> 3) & 127, j = idx & 7;
        int k  = hi * 8 + j;
        float v = (k < 27) ? cw[cout * 27 + k] : 0.f;
        wcf[(hi * 128 + cout) * 8 + j] = __float2bfloat16(v);
    }
}

// ---------- Kernel 2: fully fused conv3x3s2+relu -> qkv -> 7x7 NAT ---------------------
// One block per 4x4 output tile (784 blocks), 47.4 KB LDS -> 3 blocks/CU.
// r8 structure with the chunk loop FULLY UNROLLED so l[cc][rg] is register-allocated
// (rolled loop made it runtime-indexed -> scratch spill -> 45 MB of HBM traffic).
#define VPITCH 272   // bytes per vT / attnW row (136 shorts)
#define XPITCH 24    // shorts per x_lds row
#define XCH    504   // 21*24 shorts per channel

__global__ __launch_bounds__(256, 3) void fused_kernel(
    const float* __restrict__ x, const __hip_bfloat16* __restrict__ wcf,
    const float* __restrict__ cb, const __hip_bfloat16* __restrict__ wqkv,
    const float* __restrict__ qb, const float* __restrict__ kb,
    const float* __restrict__ vb, float* __restrict__ out)
{
    __shared__ __align__(16) short vT[128 * 136];      // 34816 B (XOR bits 4-6, pitch 272)
    __shared__ __align__(16) short poolA[16 * 128];    //  4096 B: q_lds, then k_chunk
    __shared__ __align__(16) short f_ch[16 * 128];     //  4096 B
    __shared__ __align__(16) short poolB[16 * 136];    //  4352 B: x_lds, then attnW
    short* q_lds   = poolA;
    short* k_chunk = poolA;
    short* x_lds   = poolB;
    short* attnW   = poolB;

    int t = threadIdx.x, lane = t & 63, wid = t >> 6;
    int r16 = lane & 15, hi = lane >> 4;

    int bx = blockIdx.x;                 // 4 * 196
    int b  = bx / 196;
    int rr = bx % 196;
    int th = rr / 14, tw = rr % 14;
    int ih0 = min(max(th*4 - 3, 0), HW - 10);
    int iw0 = min(max(tw*4 - 3, 0), HW - 10);

    // ---- stage x patch: 3ch x 21x21 f32 -> bf16 LDS, zero-filled at borders ----
    {
        int ihA = 2*ih0 - 1, iwA = 2*iw0 - 1;
        #pragma unroll
        for (int it = 0; it < 6; ++it) {
            int i = t + 256*it;            // 0..1535, 1512 used
            if (i < 1512) {
                int ci = i / XCH, r = i % XCH;
                int row = r / XPITCH, col = r % XPITCH;
                int ih = ihA + row, iw = iwA + col;
                float xv = 0.f;
                if (col < 21 && ih >= 0 && ih < 112 && iw >= 0 && iw < 112)
                    xv = x[((size_t)(b*3 + ci)*112 + ih)*112 + iw];
                x_lds[i] = bfbits(xv);
            }
        }
    }

    // zero vT LOGICAL units 14,15 (n in [112,128) — never written, read by PV)
    for (int i = t; i < 1024; i += 256) {
        int c = i >> 3, j = i & 7;
        int hsw = (c >> 3) & 7;
        int unit = (14 + (j >> 2)) ^ hsw;
        *(unsigned*)((char*)vT + c*VPITCH + (unit << 4) + (j & 3)*4) = 0u;
    }

    // ---- hoisted per-lane constants: im2col offsets, biases, conv B-frags ----
    int cout0 = (wid*2 + 0)*16 + r16;
    int cout1 = (wid*2 + 1)*16 + r16;
    short8 cbw0 = *(const short8*)((const short*)wcf + (hi*128 + cout0)*8);
    short8 cbw1 = *(const short8*)((const short*)wcf + (hi*128 + cout1)*8);
    float cbias0 = cb[cout0], cbias1 = cb[cout1];

    int  offb[8];
    bool vmask[8];
    #pragma unroll
    for (int j = 0; j < 8; ++j) {
        int k = hi*8 + j;
        int ci = k/9, r9 = k%9, kh = r9/3, kw_ = r9%3;
        offb[j]  = ci*XCH + kh*XPITCH + kw_;
        vmask[j] = (k < 27);
    }

    float kvbias[4];
    #pragma unroll
    for (int i = 0; i < 4; ++i) {
        int idx = wid*4 + i, mv = idx >> 3, ct = idx & 7, c = ct*16 + r16;
        kvbias[i] = mv ? vb[c] : kb[c];
    }
    float qbias[2];
    #pragma unroll
    for (int i = 0; i < 2; ++i) qbias[i] = qb[(wid*2 + i)*16 + r16];

    __syncthreads();   // x_lds ready

    // conv for one 16-pixel chunk (lane row r16 -> LOCAL window pixel (hl,wl)) into f_ch
    auto conv_to_fch = [&](int hl, int wl) {
        int pb = hl*(2*XPITCH) + wl*2;
        short8 af;
        #pragma unroll
        for (int j = 0; j < 8; ++j)
            af[j] = vmask[j] ? x_lds[offb[j] + pb] : (short)0;
        #pragma unroll
        for (int ctl = 0; ctl < 2; ++ctl) {
            int cout   = ctl ? cout1  : cout0;
            short8 bw  = ctl ? cbw1   : cbw0;
            float bias = ctl ? cbias1 : cbias0;
            f32x4 acc = {0.f, 0.f, 0.f, 0.f};
            acc = __builtin_amdgcn_mfma_f32_16x16x32_bf16(af, bw, acc, 0, 0, 0);
            int colblk = cout >> 3, inb = (cout & 7)*2;
            #pragma unroll
            for (int rg = 0; rg < 4; ++rg) {
                int px = hi*4 + rg;
                *(short*)((char*)f_ch + px*256 + ((colblk ^ px) << 4) + inb)
                    = bfbits(fmaxf(acc[rg] + bias, 0.f));
            }
        }
    };

    // ---- Q phase: conv + GEMM for the 16 center pixels -> qa registers ----
    short8 qa[4];
    {
        int ph = th*4 + (r16 >> 2), pw = tw*4 + (r16 & 3);
        conv_to_fch(ph - ih0, pw - iw0);
        __syncthreads();

        short8 fa[4];
        #pragma unroll
        for (int kk = 0; kk < 4; ++kk)
            fa[kk] = *(const short8*)((char*)f_ch + r16*256 + (((kk*4 + hi) ^ r16) << 4));

        #pragma unroll
        for (int i = 0; i < 2; ++i) {
            int ct = wid*2 + i;
            const short* wb = (const short*)wqkv + hi*1024 + r16*8 + ct*128;
            f32x4 acc = {0.f, 0.f, 0.f, 0.f};
            acc = __builtin_amdgcn_mfma_f32_16x16x32_bf16(fa[0], *(const short8*)(wb),         acc, 0, 0, 0);
            acc = __builtin_amdgcn_mfma_f32_16x16x32_bf16(fa[1], *(const short8*)(wb +  4096), acc, 0, 0, 0);
            acc = __builtin_amdgcn_mfma_f32_16x16x32_bf16(fa[2], *(const short8*)(wb +  8192), acc, 0, 0, 0);
            acc = __builtin_amdgcn_mfma_f32_16x16x32_bf16(fa[3], *(const short8*)(wb + 12288), acc, 0, 0, 0);
            int c = ct*16 + r16;
            float bb = qbias[i];
            #pragma unroll
            for (int rg = 0; rg < 4; ++rg) {
                int px = hi*4 + rg;
                *(short*)((char*)q_lds + px*256 + (((c >> 3) ^ px) << 4) + (c & 7)*2)
                    = bfbits(acc[rg] + bb);
            }
        }
        __syncthreads();

        #pragma unroll
        for (int kk = 0; kk < 4; ++kk)
            qa[kk] = *(const short8*)((char*)q_lds + r16*256 + (((kk*4 + hi) ^ r16) << 4));
        // qa reads complete before next __syncthreads(); k_chunk aliasing is then safe
    }

    // ---- halo chunks 0..6 (FULLY UNROLLED): conv -> K/V GEMM -> QK^T into registers ----
    float l[7][4];
    #pragma unroll
    for (int cc = 0; cc < 7; ++cc) {
        int nc = min(cc*16 + r16, 99);
        conv_to_fch(nc/10, nc%10);
        __syncthreads();                               // f_ch ready; k_chunk free

        short8 fa[4];
        #pragma unroll
        for (int kk = 0; kk < 4; ++kk)
            fa[kk] = *(const short8*)((char*)f_ch + r16*256 + (((kk*4 + hi) ^ r16) << 4));

        #pragma unroll
        for (int i = 0; i < 4; ++i) {
            int idx = wid*4 + i;       // 0..15, wave-uniform
            int mv  = idx >> 3;        // 0 = k, 1 = v
            int ct  = idx & 7;
            const short* wb = (const short*)wqkv + (1+mv)*16384 + hi*1024 + r16*8 + ct*128;
            f32x4 acc = {0.f, 0.f, 0.f, 0.f};
            acc = __builtin_amdgcn_mfma_f32_16x16x32_bf16(fa[0], *(const short8*)(wb),         acc, 0, 0, 0);
            acc = __builtin_amdgcn_mfma_f32_16x16x32_bf16(fa[1], *(const short8*)(wb +  4096), acc, 0, 0, 0);
            acc = __builtin_amdgcn_mfma_f32_16x16x32_bf16(fa[2], *(const short8*)(wb +  8192), acc, 0, 0, 0);
            acc = __builtin_amdgcn_mfma_f32_16x16x32_bf16(fa[3], *(const short8*)(wb + 12288), acc, 0, 0, 0);
            int c = ct*16 + r16;
            float bb = kvbias[i];
            if (mv == 0) {
                int swz = c >> 3;
                #pragma unroll
                for (int rg = 0; rg < 4; ++rg) {
                    int nl = hi*4 + rg;                // n & 15
                    *(short*)((char*)k_chunk + nl*256 + ((swz ^ nl) << 4) + (c & 7)*2)
                        = bfbits(acc[rg] + bb);
                }
            } else {
                int n0 = cc*16 + hi*4;
                unsigned lo  = packbf(acc[0] + bb, acc[1] + bb);
                unsigned hi2 = packbf(acc[2] + bb, acc[3] + bb);
                int hsw = (c >> 3) & 7;
                int off = (2*n0) ^ (hsw << 4);
                *(uint2*)((char*)vT + c*VPITCH + off) = make_uint2(lo, hi2);
            }
        }
        __syncthreads();                               // k_chunk ready

        // QK^T for this chunk: every wave computes the full 16x16 tile (redundant)
        {
            const char* kbase = (const char*)k_chunk + r16*256;
            f32x4 acc = {0.f, 0.f, 0.f, 0.f};
            #pragma unroll
            for (int kk = 0; kk < 4; ++kk) {
                short8 kv = *(const short8*)(kbase + (((kk*4 + hi) ^ r16) << 4));
                acc = __builtin_amdgcn_mfma_f32_16x16x32_bf16(qa[kk], kv, acc, 0, 0, 0);
            }
            #pragma unroll
            for (int rg = 0; rg < 4; ++rg) l[cc][rg] = acc[rg];
        }
    }

    // ---- in-register softmax per px (16-lane shfl reduce), scatter bf16 to attnW ----
    // lane holds logit[px=hi*4+rg][n=cc*16+r16]
    {
        const float scale = 0.08838834764831845f;   // 128^-0.5
        #pragma unroll
        for (int rg = 0; rg < 4; ++rg) {
            int px = hi*4 + rg;
            int h = th*4 + (px >> 2), w = tw*4 + (px & 3);
            int r0 = min(max(h - 3, 0), HW - 7) - ih0;   // window start, local coords
            int c0 = min(max(w - 3, 0), HW - 7) - iw0;
            float lv[7]; bool vn[7];
            float m = -INFINITY;
            #pragma unroll
            for (int cc = 0; cc < 7; ++cc) {
                int n  = cc*16 + r16;
                int nr = n / 10, ncl = n - nr*10;
                vn[cc] = (n < 100) && ((unsigned)(nr - r0) < 7u) && ((unsigned)(ncl - c0) < 7u);
                lv[cc] = l[cc][rg] * scale;
                if (vn[cc]) m = fmaxf(m, lv[cc]);
            }
            #pragma unroll
            for (int d = 1; d < 16; d <<= 1) m = fmaxf(m, __shfl_xor(m, d));
            float e[7]; float s = 0.f;
            #pragma unroll
            for (int cc = 0; cc < 7; ++cc) {
                e[cc] = vn[cc] ? __expf(lv[cc] - m) : 0.f;
                s += e[cc];
            }
            #pragma unroll
            for (int d = 1; d < 16; d <<= 1) s += __shfl_xor(s, d);
            float rs = 1.f / s;
            #pragma unroll
            for (int cc = 0; cc < 7; ++cc) {
                if ((cc & 3) == wid)    // each n-column written by exactly one wave
                    *(short*)((char*)attnW + px*VPITCH + 2*(cc*16 + r16)) = bfbits(e[cc] * rs);
            }
        }
        // zero attnW tail: n in [112,128) (bytes [224,256) per row), read by pa
        for (int i = t; i < 128; i += 256) {
            int row = i >> 3, j = i & 7;
            *(unsigned*)((char*)attnW + row*VPITCH + 224 + j*4) = 0u;
        }
    }
    __syncthreads();

    // ---- PV: out[16][128] = attnW x vT^T ----
    short8 pa[4];
    #pragma unroll
    for (int kk = 0; kk < 4; ++kk)
        pa[kk] = *(const short8*)((char*)attnW + r16*VPITCH + kk*64 + hi*16);

    for (int nt = wid; nt < 8; nt += 4) {
        int c   = nt*16 + r16;
        int hsw = (c >> 3) & 7;
        const char* vrow = (const char*)vT + c*VPITCH;
        f32x4 acc = {0.f, 0.f, 0.f, 0.f};
        #pragma unroll
        for (int kk = 0; kk < 4; ++kk) {
            short8 vbr = *(const short8*)(vrow + ((kk*64 + hi*16) ^ (hsw << 4)));
            acc = __builtin_amdgcn_mfma_f32_16x16x32_bf16(pa[kk], vbr, acc, 0, 0, 0);
        }
        #pragma unroll
        for (int rg = 0; rg < 4; ++rg) {
            int p = hi*4 + rg;
            int h = th*4 + (p >> 2), w = tw*4 + (p & 3);
            out[(((size_t)b*C + c)*HW + h)*HW + w] = acc[rg];
        }
    }
}

extern "C" void kernel_launch(void* const* d_in, const int* in_sizes, int n_in,
                              void* d_out, int out_size, void* d_ws, size_t ws_size,
                              hipStream_t stream) {
    const float* x      = (const float*)d_in[0];
    const float* conv_w = (const float*)d_in[1];
    const float* conv_b = (const float*)d_in[2];
    const float* q_w    = (const float*)d_in[3];
    const float* q_b    = (const float*)d_in[4];
    const float* k_w    = (const float*)d_in[5];
    const float* k_b    = (const float*)d_in[6];
    const float* v_w    = (const float*)d_in[7];
    const float* v_b    = (const float*)d_in[8];
    float* out = (float*)d_out;

    __hip_bfloat16* wqkv = (__hip_bfloat16*)d_ws;        // 3*16384
    __hip_bfloat16* wcf  = wqkv + 3 * 16384;             // 4096

    prep_kernel<<<208, 256, 0, stream>>>(conv_w, q_w, k_w, v_w, wcf, wqkv);
    fused_kernel<<<NB*196, 256, 0, stream>>>(x, wcf, conv_b, wqkv,
                                             q_b, k_b, v_b, out);
}

// Round 10
// 47.565 us; speedup vs baseline: 1.5569x; 1.3144x over previous
//
#include <hip/hip_runtime.h>
#include <hip/hip_bf16.h>
#include <math.h>

#define HW 56
#define PPI (HW*HW)          // 3136 pixels per image
#define NB 4
#define C 128
#define NPIX (NB*PPI)        // 12544

typedef __attribute__((ext_vector_type(8))) short short8;
typedef __attribute__((ext_vector_type(4))) float f32x4;

__device__ __forceinline__ short bfbits(float v) {
    __hip_bfloat16 hb = __float2bfloat16(v);
    return *reinterpret_cast<short*>(&hb);
}
__device__ __forceinline__ unsigned packbf(float a, float b) {
    return (unsigned)(unsigned short)bfbits(a) | ((unsigned)(unsigned short)bfbits(b) << 16);
}

// ---------- Kernel 1: weight prep (qkv B-frags + conv B-frags) — unchanged -------------
__global__ __launch_bounds__(256) void prep_kernel(
    const float* __restrict__ cw,
    const float* __restrict__ qw, const float* __restrict__ kw,
    const float* __restrict__ vw,
    __hip_bfloat16* __restrict__ wcf, __hip_bfloat16* __restrict__ wqkv)
{
    int gid = blockIdx.x * 256 + threadIdx.x;
    if (blockIdx.x < 192) {
        int m   = gid >> 14;
        int r   = gid & 16383;
        int col = r >> 7;
        int k   = r & 127;
        const float* W = (m == 0) ? qw : (m == 1) ? kw : vw;
        int kk = k >> 5, hi = (k >> 3) & 3, j = k & 7;
        wqkv[m * 16384 + ((kk * 4 + hi) * 128 + col) * 8 + j] = __float2bfloat16(W[col * 128 + k]);
    } else {
        int idx = gid - 192 * 256;          // 0..4095
        int hi = idx >> 10, cout = (idx >> 3) & 127, j = idx & 7;
        int k  = hi * 8 + j;
        float v = (k < 27) ? cw[cout * 27 + k] : 0.f;
        wcf[(hi * 128 + cout) * 8 + j] = __float2bfloat16(v);
    }
}

// ---------- Kernel 2: fully fused conv3x3s2+relu -> qkv -> 7x7 NAT ---------------------
// One block per 4x4 output tile (784 blocks), 54528 B LDS -> 3 blocks/CU.
// Logits live in LDS (no cross-barrier register arrays -> no scratch spill):
// per halo chunk, ONE wave computes the 16x16 QK^T tile and writes logit_s.
#define VPITCH 272   // bytes per vT / attnW row (136 shorts)
#define XPITCH 24    // shorts per x_lds row
#define XCH    504   // 21*24 shorts per channel
#define LPITCH 112   // floats per logit_s row

__global__ __launch_bounds__(256, 3) void fused_kernel(
    const float* __restrict__ x, const __hip_bfloat16* __restrict__ wcf,
    const float* __restrict__ cb, const __hip_bfloat16* __restrict__ wqkv,
    const float* __restrict__ qb, const float* __restrict__ kb,
    const float* __restrict__ vb, float* __restrict__ out)
{
    __shared__ __align__(16) short vT[128 * 136];      // 34816 B (XOR bits 4-6, pitch 272)
    __shared__ __align__(16) short poolA[16 * 128];    //  4096 B: q_lds, then k_chunk
    __shared__ __align__(16) short f_ch[16 * 128];     //  4096 B
    __shared__ __align__(16) short poolB[16 * 136];    //  4352 B: x_lds, then attnW
    __shared__ __align__(16) float logit_s[16 * LPITCH];// 7168 B
    short* q_lds   = poolA;
    short* k_chunk = poolA;
    short* x_lds   = poolB;
    short* attnW   = poolB;

    int t = threadIdx.x, lane = t & 63, wid = t >> 6;
    int r16 = lane & 15, hi = lane >> 4;

    int bx = blockIdx.x;                 // 4 * 196
    int b  = bx / 196;
    int rr = bx % 196;
    int th = rr / 14, tw = rr % 14;
    int ih0 = min(max(th*4 - 3, 0), HW - 10);
    int iw0 = min(max(tw*4 - 3, 0), HW - 10);

    // ---- stage x patch: 3ch x 21x21 f32 -> bf16 LDS, zero-filled at borders ----
    {
        int ihA = 2*ih0 - 1, iwA = 2*iw0 - 1;
        #pragma unroll
        for (int it = 0; it < 6; ++it) {
            int i = t + 256*it;            // 0..1535, 1512 used
            if (i < 1512) {
                int ci = i / XCH, r = i % XCH;
                int row = r / XPITCH, col = r % XPITCH;
                int ih = ihA + row, iw = iwA + col;
                float xv = 0.f;
                if (col < 21 && ih >= 0 && ih < 112 && iw >= 0 && iw < 112)
                    xv = x[((size_t)(b*3 + ci)*112 + ih)*112 + iw];
                x_lds[i] = bfbits(xv);
            }
        }
    }

    // zero vT LOGICAL units 14,15 (n in [112,128) — never written, read by PV)
    for (int i = t; i < 1024; i += 256) {
        int c = i >> 3, j = i & 7;
        int hsw = (c >> 3) & 7;
        int unit = (14 + (j >> 2)) ^ hsw;
        *(unsigned*)((char*)vT + c*VPITCH + (unit << 4) + (j & 3)*4) = 0u;
    }

    // ---- hoisted per-lane constants: im2col offsets, biases, conv B-frags ----
    int cout0 = (wid*2 + 0)*16 + r16;
    int cout1 = (wid*2 + 1)*16 + r16;
    short8 cbw0 = *(const short8*)((const short*)wcf + (hi*128 + cout0)*8);
    short8 cbw1 = *(const short8*)((const short*)wcf + (hi*128 + cout1)*8);
    float cbias0 = cb[cout0], cbias1 = cb[cout1];

    int  offb[8];
    bool vmask[8];
    #pragma unroll
    for (int j = 0; j < 8; ++j) {
        int k = hi*8 + j;
        int ci = k/9, r9 = k%9, kh = r9/3, kw_ = r9%3;
        offb[j]  = ci*XCH + kh*XPITCH + kw_;
        vmask[j] = (k < 27);
    }

    float kvbias[4];
    #pragma unroll
    for (int i = 0; i < 4; ++i) {
        int idx = wid*4 + i, mv = idx >> 3, ct = idx & 7, c = ct*16 + r16;
        kvbias[i] = mv ? vb[c] : kb[c];
    }
    float qbias[2];
    #pragma unroll
    for (int i = 0; i < 2; ++i) qbias[i] = qb[(wid*2 + i)*16 + r16];

    __syncthreads();   // x_lds ready

    // conv for one 16-pixel chunk (lane row r16 -> LOCAL window pixel (hl,wl)) into f_ch
    auto conv_to_fch = [&](int hl, int wl) {
        int pb = hl*(2*XPITCH) + wl*2;
        short8 af;
        #pragma unroll
        for (int j = 0; j < 8; ++j)
            af[j] = vmask[j] ? x_lds[offb[j] + pb] : (short)0;
        #pragma unroll
        for (int ctl = 0; ctl < 2; ++ctl) {
            int cout   = ctl ? cout1  : cout0;
            short8 bw  = ctl ? cbw1   : cbw0;
            float bias = ctl ? cbias1 : cbias0;
            f32x4 acc = {0.f, 0.f, 0.f, 0.f};
            acc = __builtin_amdgcn_mfma_f32_16x16x32_bf16(af, bw, acc, 0, 0, 0);
            int colblk = cout >> 3, inb = (cout & 7)*2;
            #pragma unroll
            for (int rg = 0; rg < 4; ++rg) {
                int px = hi*4 + rg;
                *(short*)((char*)f_ch + px*256 + ((colblk ^ px) << 4) + inb)
                    = bfbits(fmaxf(acc[rg] + bias, 0.f));
            }
        }
    };

    // ---- Q phase: conv + GEMM for the 16 center pixels -> qa registers ----
    short8 qa[4];
    {
        int ph = th*4 + (r16 >> 2), pw = tw*4 + (r16 & 3);
        conv_to_fch(ph - ih0, pw - iw0);
        __syncthreads();

        short8 fa[4];
        #pragma unroll
        for (int kk = 0; kk < 4; ++kk)
            fa[kk] = *(const short8*)((char*)f_ch + r16*256 + (((kk*4 + hi) ^ r16) << 4));

        #pragma unroll
        for (int i = 0; i < 2; ++i) {
            int ct = wid*2 + i;
            const short* wb = (const short*)wqkv + hi*1024 + r16*8 + ct*128;
            f32x4 acc = {0.f, 0.f, 0.f, 0.f};
            acc = __builtin_amdgcn_mfma_f32_16x16x32_bf16(fa[0], *(const short8*)(wb),         acc, 0, 0, 0);
            acc = __builtin_amdgcn_mfma_f32_16x16x32_bf16(fa[1], *(const short8*)(wb +  4096), acc, 0, 0, 0);
            acc = __builtin_amdgcn_mfma_f32_16x16x32_bf16(fa[2], *(const short8*)(wb +  8192), acc, 0, 0, 0);
            acc = __builtin_amdgcn_mfma_f32_16x16x32_bf16(fa[3], *(const short8*)(wb + 12288), acc, 0, 0, 0);
            int c = ct*16 + r16;
            float bb = qbias[i];
            #pragma unroll
            for (int rg = 0; rg < 4; ++rg) {
                int px = hi*4 + rg;
                *(short*)((char*)q_lds + px*256 + (((c >> 3) ^ px) << 4) + (c & 7)*2)
                    = bfbits(acc[rg] + bb);
            }
        }
        __syncthreads();

        #pragma unroll
        for (int kk = 0; kk < 4; ++kk)
            qa[kk] = *(const short8*)((char*)q_lds + r16*256 + (((kk*4 + hi) ^ r16) << 4));
        // qa reads complete before the next __syncthreads(); k_chunk aliasing then safe
    }

    // ---- halo chunks 0..6 (rolled): conv -> K/V GEMM -> QK^T (one wave) -> logit_s ----
    for (int cc = 0; cc < 7; ++cc) {
        int nc = min(cc*16 + r16, 99);
        conv_to_fch(nc/10, nc%10);
        __syncthreads();                               // S1: f_ch ready; k_chunk free

        short8 fa[4];
        #pragma unroll
        for (int kk = 0; kk < 4; ++kk)
            fa[kk] = *(const short8*)((char*)f_ch + r16*256 + (((kk*4 + hi) ^ r16) << 4));

        #pragma unroll
        for (int i = 0; i < 4; ++i) {
            int idx = wid*4 + i;       // 0..15, wave-uniform
            int mv  = idx >> 3;        // 0 = k, 1 = v
            int ct  = idx & 7;
            const short* wb = (const short*)wqkv + (1+mv)*16384 + hi*1024 + r16*8 + ct*128;
            f32x4 acc = {0.f, 0.f, 0.f, 0.f};
            acc = __builtin_amdgcn_mfma_f32_16x16x32_bf16(fa[0], *(const short8*)(wb),         acc, 0, 0, 0);
            acc = __builtin_amdgcn_mfma_f32_16x16x32_bf16(fa[1], *(const short8*)(wb +  4096), acc, 0, 0, 0);
            acc = __builtin_amdgcn_mfma_f32_16x16x32_bf16(fa[2], *(const short8*)(wb +  8192), acc, 0, 0, 0);
            acc = __builtin_amdgcn_mfma_f32_16x16x32_bf16(fa[3], *(const short8*)(wb + 12288), acc, 0, 0, 0);
            int c = ct*16 + r16;
            float bb = kvbias[i];
            if (mv == 0) {
                int swz = c >> 3;
                #pragma unroll
                for (int rg = 0; rg < 4; ++rg) {
                    int nl = hi*4 + rg;                // n & 15
                    *(short*)((char*)k_chunk + nl*256 + ((swz ^ nl) << 4) + (c & 7)*2)
                        = bfbits(acc[rg] + bb);
                }
            } else {
                int n0 = cc*16 + hi*4;
                unsigned lo  = packbf(acc[0] + bb, acc[1] + bb);
                unsigned hi2 = packbf(acc[2] + bb, acc[3] + bb);
                int hsw = (c >> 3) & 7;
                int off = (2*n0) ^ (hsw << 4);
                *(uint2*)((char*)vT + c*VPITCH + off) = make_uint2(lo, hi2);
            }
        }
        __syncthreads();                               // S2: k_chunk ready

        // QK^T for this chunk: one wave computes the 16x16 tile, writes logit_s
        if ((cc & 3) == wid) {
            const char* kbase = (const char*)k_chunk + r16*256;
            f32x4 acc = {0.f, 0.f, 0.f, 0.f};
            #pragma unroll
            for (int kk = 0; kk < 4; ++kk) {
                short8 kv = *(const short8*)(kbase + (((kk*4 + hi) ^ r16) << 4));
                acc = __builtin_amdgcn_mfma_f32_16x16x32_bf16(qa[kk], kv, acc, 0, 0, 0);
            }
            #pragma unroll
            for (int rg = 0; rg < 4; ++rg)
                logit_s[(hi*4 + rg)*LPITCH + cc*16 + r16] = acc[rg];
        }
    }

    // ---- zero attnW (x_lds dead: last read before chunk-6 S1) ----
    {
        unsigned* aw = (unsigned*)attnW;
        for (int i = t; i < 1088; i += 256) aw[i] = 0u;
    }
    __syncthreads();   // S3: logit_s complete, attnW zeroed

    // ---- softmax per pixel (4 px per wave, lane=neighbor), scatter bf16 to attnW ----
    {
        int r7 = lane / 7, s7 = lane - 7*r7;
        bool valid = lane < 49;
        const float scale = 0.08838834764831845f;   // 128^-0.5
        #pragma unroll
        for (int px = 0; px < 4; ++px) {
            int p = wid*4 + px;
            int h = th*4 + (p >> 2), w = tw*4 + (p & 3);
            int hs = min(max(h - 3, 0), HW - 7);
            int ws = min(max(w - 3, 0), HW - 7);
            int col = (hs - ih0 + r7)*10 + (ws - iw0 + s7);
            float lg = valid ? logit_s[p*LPITCH + col] * scale : -INFINITY;
            float m = lg;
            #pragma unroll
            for (int d = 1; d < 64; d <<= 1) m = fmaxf(m, __shfl_xor(m, d));
            float e = valid ? __expf(lg - m) : 0.f;
            float s = e;
            #pragma unroll
            for (int d = 1; d < 64; d <<= 1) s += __shfl_xor(s, d);
            if (valid) {
                __hip_bfloat16 hb = __float2bfloat16(e / s);
                *(__hip_bfloat16*)((char*)attnW + p*VPITCH + 2*col) = hb;
            }
        }
    }
    __syncthreads();   // S4: attnW ready

    // ---- PV: out[16][128] = attnW x vT^T ----
    short8 pa[4];
    #pragma unroll
    for (int kk = 0; kk < 4; ++kk)
        pa[kk] = *(const short8*)((char*)attnW + r16*VPITCH + kk*64 + hi*16);

    for (int nt = wid; nt < 8; nt += 4) {
        int c   = nt*16 + r16;
        int hsw = (c >> 3) & 7;
        const char* vrow = (const char*)vT + c*VPITCH;
        f32x4 acc = {0.f, 0.f, 0.f, 0.f};
        #pragma unroll
        for (int kk = 0; kk < 4; ++kk) {
            short8 vbr = *(const short8*)(vrow + ((kk*64 + hi*16) ^ (hsw << 4)));
            acc = __builtin_amdgcn_mfma_f32_16x16x32_bf16(pa[kk], vbr, acc, 0, 0, 0);
        }
        #pragma unroll
        for (int rg = 0; rg < 4; ++rg) {
            int p = hi*4 + rg;
            int h = th*4 + (p >> 2), w = tw*4 + (p & 3);
            out[(((size_t)b*C + c)*HW + h)*HW + w] = acc[rg];
        }
    }
}

extern "C" void kernel_launch(void* const* d_in, const int* in_sizes, int n_in,
                              void* d_out, int out_size, void* d_ws, size_t ws_size,
                              hipStream_t stream) {
    const float* x      = (const float*)d_in[0];
    const float* conv_w = (const float*)d_in[1];
    const float* conv_b = (const float*)d_in[2];
    const float* q_w    = (const float*)d_in[3];
    const float* q_b    = (const float*)d_in[4];
    const float* k_w    = (const float*)d_in[5];
    const float* k_b    = (const float*)d_in[6];
    const float* v_w    = (const float*)d_in[7];
    const float* v_b    = (const float*)d_in[8];
    float* out = (float*)d_out;

    __hip_bfloat16* wqkv = (__hip_bfloat16*)d_ws;        // 3*16384
    __hip_bfloat16* wcf  = wqkv + 3 * 16384;             // 4096

    prep_kernel<<<208, 256, 0, stream>>>(conv_w, q_w, k_w, v_w, wcf, wqkv);
    fused_kernel<<<NB*196, 256, 0, stream>>>(x, wcf, conv_b, wqkv,
                                             q_b, k_b, v_b, out);
}

// Round 11
// 45.680 us; speedup vs baseline: 1.6211x; 1.0413x over previous
//
#include <hip/hip_runtime.h>
#include <hip/hip_bf16.h>
#include <math.h>

#define HW 56
#define PPI (HW*HW)          // 3136 pixels per image
#define NB 4
#define C 128
#define NPIX (NB*PPI)        // 12544

typedef __attribute__((ext_vector_type(8))) short short8;
typedef __attribute__((ext_vector_type(4))) float f32x4;

__device__ __forceinline__ short bfbits(float v) {
    __hip_bfloat16 hb = __float2bfloat16(v);
    return *reinterpret_cast<short*>(&hb);
}
__device__ __forceinline__ unsigned packbf(float a, float b) {
    return (unsigned)(unsigned short)bfbits(a) | ((unsigned)(unsigned short)bfbits(b) << 16);
}

// ---------- Kernel 1: weight prep (qkv B-frags + conv B-frags) — unchanged -------------
__global__ __launch_bounds__(256) void prep_kernel(
    const float* __restrict__ cw,
    const float* __restrict__ qw, const float* __restrict__ kw,
    const float* __restrict__ vw,
    __hip_bfloat16* __restrict__ wcf, __hip_bfloat16* __restrict__ wqkv)
{
    int gid = blockIdx.x * 256 + threadIdx.x;
    if (blockIdx.x < 192) {
        int m   = gid >> 14;
        int r   = gid & 16383;
        int col = r >> 7;
        int k   = r & 127;
        const float* W = (m == 0) ? qw : (m == 1) ? kw : vw;
        int kk = k >> 5, hi = (k >> 3) & 3, j = k & 7;
        wqkv[m * 16384 + ((kk * 4 + hi) * 128 + col) * 8 + j] = __float2bfloat16(W[col * 128 + k]);
    } else {
        int idx = gid - 192 * 256;          // 0..4095
        int hi = idx >> 10, cout = (idx >> 3) & 127, j = idx & 7;
        int k  = hi * 8 + j;
        float v = (k < 27) ? cw[cout * 27 + k] : 0.f;
        wcf[(hi * 128 + cout) * 8 + j] = __float2bfloat16(v);
    }
}

// ---------- Kernel 2: fully fused conv3x3s2+relu -> qkv -> 7x7 NAT ---------------------
// One block per 4x4 output tile (784 blocks), 53760 B LDS = 105*512 -> 3 blocks/CU
// (512-B LDS allocation granularity; 53760*3 = 161280 <= 163840).
#define VPITCH 272   // bytes per vT / attnW row (136 shorts)
#define XPITCH 24    // shorts per x_lds row
#define XCH    504   // 21*24 shorts per channel
#define LPITCH 100   // floats per logit_s row (valid neighbor idx < 100)

__global__ __launch_bounds__(256, 3) void fused_kernel(
    const float* __restrict__ x, const __hip_bfloat16* __restrict__ wcf,
    const float* __restrict__ cb, const __hip_bfloat16* __restrict__ wqkv,
    const float* __restrict__ qb, const float* __restrict__ kb,
    const float* __restrict__ vb, float* __restrict__ out)
{
    __shared__ __align__(16) short vT[128 * 136];      // 34816 B (XOR bits 4-6, pitch 272)
    __shared__ __align__(16) short poolA[16 * 128];    //  4096 B: q_lds, then k_chunk
    __shared__ __align__(16) short f_ch[16 * 128];     //  4096 B
    __shared__ __align__(16) short poolB[16 * 136];    //  4352 B: x_lds, then attnW
    __shared__ __align__(16) float logit_s[16 * LPITCH];// 6400 B
    short* q_lds   = poolA;
    short* k_chunk = poolA;
    short* x_lds   = poolB;
    short* attnW   = poolB;

    int t = threadIdx.x, lane = t & 63, wid = t >> 6;
    int r16 = lane & 15, hi = lane >> 4;

    int bx = blockIdx.x;                 // 4 * 196
    int b  = bx / 196;
    int rr = bx % 196;
    int th = rr / 14, tw = rr % 14;
    int ih0 = min(max(th*4 - 3, 0), HW - 10);
    int iw0 = min(max(tw*4 - 3, 0), HW - 10);

    // ---- stage x patch: 3ch x 21x21 f32 -> bf16 LDS, zero-filled at borders ----
    {
        int ihA = 2*ih0 - 1, iwA = 2*iw0 - 1;
        #pragma unroll
        for (int it = 0; it < 6; ++it) {
            int i = t + 256*it;            // 0..1535, 1512 used
            if (i < 1512) {
                int ci = i / XCH, r = i % XCH;
                int row = r / XPITCH, col = r % XPITCH;
                int ih = ihA + row, iw = iwA + col;
                float xv = 0.f;
                if (col < 21 && ih >= 0 && ih < 112 && iw >= 0 && iw < 112)
                    xv = x[((size_t)(b*3 + ci)*112 + ih)*112 + iw];
                x_lds[i] = bfbits(xv);
            }
        }
    }

    // zero vT LOGICAL units 14,15 (n in [112,128) — never written, read by PV)
    for (int i = t; i < 1024; i += 256) {
        int c = i >> 3, j = i & 7;
        int hsw = (c >> 3) & 7;
        int unit = (14 + (j >> 2)) ^ hsw;
        *(unsigned*)((char*)vT + c*VPITCH + (unit << 4) + (j & 3)*4) = 0u;
    }

    // ---- hoisted per-lane constants: im2col offsets, biases, conv B-frags ----
    int cout0 = (wid*2 + 0)*16 + r16;
    int cout1 = (wid*2 + 1)*16 + r16;
    short8 cbw0 = *(const short8*)((const short*)wcf + (hi*128 + cout0)*8);
    short8 cbw1 = *(const short8*)((const short*)wcf + (hi*128 + cout1)*8);
    float cbias0 = cb[cout0], cbias1 = cb[cout1];

    int  offb[8];
    bool vmask[8];
    #pragma unroll
    for (int j = 0; j < 8; ++j) {
        int k = hi*8 + j;
        int ci = k/9, r9 = k%9, kh = r9/3, kw_ = r9%3;
        offb[j]  = ci*XCH + kh*XPITCH + kw_;
        vmask[j] = (k < 27);
    }

    float kvbias[4];
    #pragma unroll
    for (int i = 0; i < 4; ++i) {
        int idx = wid*4 + i, mv = idx >> 3, ct = idx & 7, c = ct*16 + r16;
        kvbias[i] = mv ? vb[c] : kb[c];
    }
    float qbias[2];
    #pragma unroll
    for (int i = 0; i < 2; ++i) qbias[i] = qb[(wid*2 + i)*16 + r16];

    __syncthreads();   // x_lds ready

    // conv for one 16-pixel chunk (lane row r16 -> LOCAL window pixel (hl,wl)) into f_ch
    auto conv_to_fch = [&](int hl, int wl) {
        int pb = hl*(2*XPITCH) + wl*2;
        short8 af;
        #pragma unroll
        for (int j = 0; j < 8; ++j)
            af[j] = vmask[j] ? x_lds[offb[j] + pb] : (short)0;
        #pragma unroll
        for (int ctl = 0; ctl < 2; ++ctl) {
            int cout   = ctl ? cout1  : cout0;
            short8 bw  = ctl ? cbw1   : cbw0;
            float bias = ctl ? cbias1 : cbias0;
            f32x4 acc = {0.f, 0.f, 0.f, 0.f};
            acc = __builtin_amdgcn_mfma_f32_16x16x32_bf16(af, bw, acc, 0, 0, 0);
            int colblk = cout >> 3, inb = (cout & 7)*2;
            #pragma unroll
            for (int rg = 0; rg < 4; ++rg) {
                int px = hi*4 + rg;
                *(short*)((char*)f_ch + px*256 + ((colblk ^ px) << 4) + inb)
                    = bfbits(fmaxf(acc[rg] + bias, 0.f));
            }
        }
    };

    // ---- Q phase: conv + GEMM for the 16 center pixels -> qa registers ----
    short8 qa[4];
    {
        int ph = th*4 + (r16 >> 2), pw = tw*4 + (r16 & 3);
        conv_to_fch(ph - ih0, pw - iw0);
        __syncthreads();

        short8 fa[4];
        #pragma unroll
        for (int kk = 0; kk < 4; ++kk)
            fa[kk] = *(const short8*)((char*)f_ch + r16*256 + (((kk*4 + hi) ^ r16) << 4));

        #pragma unroll
        for (int i = 0; i < 2; ++i) {
            int ct = wid*2 + i;
            const short* wb = (const short*)wqkv + hi*1024 + r16*8 + ct*128;
            f32x4 acc = {0.f, 0.f, 0.f, 0.f};
            acc = __builtin_amdgcn_mfma_f32_16x16x32_bf16(fa[0], *(const short8*)(wb),         acc, 0, 0, 0);
            acc = __builtin_amdgcn_mfma_f32_16x16x32_bf16(fa[1], *(const short8*)(wb +  4096), acc, 0, 0, 0);
            acc = __builtin_amdgcn_mfma_f32_16x16x32_bf16(fa[2], *(const short8*)(wb +  8192), acc, 0, 0, 0);
            acc = __builtin_amdgcn_mfma_f32_16x16x32_bf16(fa[3], *(const short8*)(wb + 12288), acc, 0, 0, 0);
            int c = ct*16 + r16;
            float bb = qbias[i];
            #pragma unroll
            for (int rg = 0; rg < 4; ++rg) {
                int px = hi*4 + rg;
                *(short*)((char*)q_lds + px*256 + (((c >> 3) ^ px) << 4) + (c & 7)*2)
                    = bfbits(acc[rg] + bb);
            }
        }
        __syncthreads();

        #pragma unroll
        for (int kk = 0; kk < 4; ++kk)
            qa[kk] = *(const short8*)((char*)q_lds + r16*256 + (((kk*4 + hi) ^ r16) << 4));
        // qa reads complete before the next __syncthreads(); k_chunk aliasing then safe
    }

    // ---- halo chunks 0..6 (rolled): conv -> K/V GEMM -> QK^T (one wave) -> logit_s ----
    for (int cc = 0; cc < 7; ++cc) {
        int nc = min(cc*16 + r16, 99);
        conv_to_fch(nc/10, nc%10);
        __syncthreads();                               // S1: f_ch ready; k_chunk free

        short8 fa[4];
        #pragma unroll
        for (int kk = 0; kk < 4; ++kk)
            fa[kk] = *(const short8*)((char*)f_ch + r16*256 + (((kk*4 + hi) ^ r16) << 4));

        #pragma unroll
        for (int i = 0; i < 4; ++i) {
            int idx = wid*4 + i;       // 0..15, wave-uniform
            int mv  = idx >> 3;        // 0 = k, 1 = v
            int ct  = idx & 7;
            const short* wb = (const short*)wqkv + (1+mv)*16384 + hi*1024 + r16*8 + ct*128;
            f32x4 acc = {0.f, 0.f, 0.f, 0.f};
            acc = __builtin_amdgcn_mfma_f32_16x16x32_bf16(fa[0], *(const short8*)(wb),         acc, 0, 0, 0);
            acc = __builtin_amdgcn_mfma_f32_16x16x32_bf16(fa[1], *(const short8*)(wb +  4096), acc, 0, 0, 0);
            acc = __builtin_amdgcn_mfma_f32_16x16x32_bf16(fa[2], *(const short8*)(wb +  8192), acc, 0, 0, 0);
            acc = __builtin_amdgcn_mfma_f32_16x16x32_bf16(fa[3], *(const short8*)(wb + 12288), acc, 0, 0, 0);
            int c = ct*16 + r16;
            float bb = kvbias[i];
            if (mv == 0) {
                int swz = c >> 3;
                #pragma unroll
                for (int rg = 0; rg < 4; ++rg) {
                    int nl = hi*4 + rg;                // n & 15
                    *(short*)((char*)k_chunk + nl*256 + ((swz ^ nl) << 4) + (c & 7)*2)
                        = bfbits(acc[rg] + bb);
                }
            } else {
                int n0 = cc*16 + hi*4;
                unsigned lo  = packbf(acc[0] + bb, acc[1] + bb);
                unsigned hi2 = packbf(acc[2] + bb, acc[3] + bb);
                int hsw = (c >> 3) & 7;
                int off = (2*n0) ^ (hsw << 4);
                *(uint2*)((char*)vT + c*VPITCH + off) = make_uint2(lo, hi2);
            }
        }
        __syncthreads();                               // S2: k_chunk ready

        // QK^T for this chunk: one wave computes the 16x16 tile, writes logit_s.
        // Guard col < 100: cols >= 100 are clamped-dup garbage and, with LPITCH=100,
        // would alias the next row's valid cols 0..3.
        if ((cc & 3) == wid) {
            const char* kbase = (const char*)k_chunk + r16*256;
            f32x4 acc = {0.f, 0.f, 0.f, 0.f};
            #pragma unroll
            for (int kk = 0; kk < 4; ++kk) {
                short8 kv = *(const short8*)(kbase + (((kk*4 + hi) ^ r16) << 4));
                acc = __builtin_amdgcn_mfma_f32_16x16x32_bf16(qa[kk], kv, acc, 0, 0, 0);
            }
            int col = cc*16 + r16;
            if (col < 100) {
                #pragma unroll
                for (int rg = 0; rg < 4; ++rg)
                    logit_s[(hi*4 + rg)*LPITCH + col] = acc[rg];
            }
        }
    }

    // ---- zero attnW (x_lds dead: last read before chunk-6 S1) ----
    {
        unsigned* aw = (unsigned*)attnW;
        for (int i = t; i < 1088; i += 256) aw[i] = 0u;
    }
    __syncthreads();   // S3: logit_s complete, attnW zeroed

    // ---- softmax per pixel (4 px per wave, lane=neighbor), scatter bf16 to attnW ----
    {
        int r7 = lane / 7, s7 = lane - 7*r7;
        bool valid = lane < 49;
        const float scale = 0.08838834764831845f;   // 128^-0.5
        #pragma unroll
        for (int px = 0; px < 4; ++px) {
            int p = wid*4 + px;
            int h = th*4 + (p >> 2), w = tw*4 + (p & 3);
            int hs = min(max(h - 3, 0), HW - 7);
            int ws = min(max(w - 3, 0), HW - 7);
            int col = (hs - ih0 + r7)*10 + (ws - iw0 + s7);
            float lg = valid ? logit_s[p*LPITCH + col] * scale : -INFINITY;
            float m = lg;
            #pragma unroll
            for (int d = 1; d < 64; d <<= 1) m = fmaxf(m, __shfl_xor(m, d));
            float e = valid ? __expf(lg - m) : 0.f;
            float s = e;
            #pragma unroll
            for (int d = 1; d < 64; d <<= 1) s += __shfl_xor(s, d);
            if (valid) {
                __hip_bfloat16 hb = __float2bfloat16(e / s);
                *(__hip_bfloat16*)((char*)attnW + p*VPITCH + 2*col) = hb;
            }
        }
    }
    __syncthreads();   // S4: attnW ready

    // ---- PV: out[16][128] = attnW x vT^T ----
    short8 pa[4];
    #pragma unroll
    for (int kk = 0; kk < 4; ++kk)
        pa[kk] = *(const short8*)((char*)attnW + r16*VPITCH + kk*64 + hi*16);

    for (int nt = wid; nt < 8; nt += 4) {
        int c   = nt*16 + r16;
        int hsw = (c >> 3) & 7;
        const char* vrow = (const char*)vT + c*VPITCH;
        f32x4 acc = {0.f, 0.f, 0.f, 0.f};
        #pragma unroll
        for (int kk = 0; kk < 4; ++kk) {
            short8 vbr = *(const short8*)(vrow + ((kk*64 + hi*16) ^ (hsw << 4)));
            acc = __builtin_amdgcn_mfma_f32_16x16x32_bf16(pa[kk], vbr, acc, 0, 0, 0);
        }
        #pragma unroll
        for (int rg = 0; rg < 4; ++rg) {
            int p = hi*4 + rg;
            int h = th*4 + (p >> 2), w = tw*4 + (p & 3);
            out[(((size_t)b*C + c)*HW + h)*HW + w] = acc[rg];
        }
    }
}

extern "C" void kernel_launch(void* const* d_in, const int* in_sizes, int n_in,
                              void* d_out, int out_size, void* d_ws, size_t ws_size,
                              hipStream_t stream) {
    const float* x      = (const float*)d_in[0];
    const float* conv_w = (const float*)d_in[1];
    const float* conv_b = (const float*)d_in[2];
    const float* q_w    = (const float*)d_in[3];
    const float* q_b    = (const float*)d_in[4];
    const float* k_w    = (const float*)d_in[5];
    const float* k_b    = (const float*)d_in[6];
    const float* v_w    = (const float*)d_in[7];
    const float* v_b    = (const float*)d_in[8];
    float* out = (float*)d_out;

    __hip_bfloat16* wqkv = (__hip_bfloat16*)d_ws;        // 3*16384
    __hip_bfloat16* wcf  = wqkv + 3 * 16384;             // 4096

    prep_kernel<<<208, 256, 0, stream>>>(conv_w, q_w, k_w, v_w, wcf, wqkv);
    fused_kernel<<<NB*196, 256, 0, stream>>>(x, wcf, conv_b, wqkv,
                                             q_b, k_b, v_b, out);
}

// Round 12
// 43.484 us; speedup vs baseline: 1.7030x; 1.0505x over previous
//
#include <hip/hip_runtime.h>
#include <hip/hip_bf16.h>
#include <math.h>

#define HW 56
#define PPI (HW*HW)          // 3136 pixels per image
#define NB 4
#define C 128
#define NPIX (NB*PPI)        // 12544

typedef __attribute__((ext_vector_type(8))) short short8;
typedef __attribute__((ext_vector_type(4))) float f32x4;

__device__ __forceinline__ short bfbits(float v) {
    __hip_bfloat16 hb = __float2bfloat16(v);
    return *reinterpret_cast<short*>(&hb);
}
__device__ __forceinline__ unsigned packbf(float a, float b) {
    return (unsigned)(unsigned short)bfbits(a) | ((unsigned)(unsigned short)bfbits(b) << 16);
}

// ---------- Kernel 1: weight prep (qkv B-frags + conv B-frags) — unchanged -------------
__global__ __launch_bounds__(256) void prep_kernel(
    const float* __restrict__ cw,
    const float* __restrict__ qw, const float* __restrict__ kw,
    const float* __restrict__ vw,
    __hip_bfloat16* __restrict__ wcf, __hip_bfloat16* __restrict__ wqkv)
{
    int gid = blockIdx.x * 256 + threadIdx.x;
    if (blockIdx.x < 192) {
        int m   = gid >> 14;
        int r   = gid & 16383;
        int col = r >> 7;
        int k   = r & 127;
        const float* W = (m == 0) ? qw : (m == 1) ? kw : vw;
        int kk = k >> 5, hi = (k >> 3) & 3, j = k & 7;
        wqkv[m * 16384 + ((kk * 4 + hi) * 128 + col) * 8 + j] = __float2bfloat16(W[col * 128 + k]);
    } else {
        int idx = gid - 192 * 256;          // 0..4095
        int hi = idx >> 10, cout = (idx >> 3) & 127, j = idx & 7;
        int k  = hi * 8 + j;
        float v = (k < 27) ? cw[cout * 27 + k] : 0.f;
        wcf[(hi * 128 + cout) * 8 + j] = __float2bfloat16(v);
    }
}

// ---------- Kernel 2: fully fused conv3x3s2+relu -> qkv -> 7x7 NAT ---------------------
// One block per 4x4 output tile (784 blocks). WAVE-OWNS-CHUNK structure: after the Q
// phase, each wave processes its halo chunks (conv -> K GEMM -> V GEMM -> QK^T) with
// ZERO barriers, using a private 4 KB LDS buffer (f then k; same-wave DS ops are
// in-order). Barriers: 7 total (was 17).
#define VPITCH 272   // bytes per vT / attnW row (136 shorts)
#define XPITCH 24    // shorts per x_lds row
#define XCH    504   // 21*24 shorts per channel
#define LPITCH 100   // floats per logit_s row (valid neighbor idx < 100)

__global__ __launch_bounds__(256, 2) void fused_kernel(
    const float* __restrict__ x, const __hip_bfloat16* __restrict__ wcf,
    const float* __restrict__ cb, const __hip_bfloat16* __restrict__ wqkv,
    const float* __restrict__ qb, const float* __restrict__ kb,
    const float* __restrict__ vb, float* __restrict__ out)
{
    __shared__ __align__(16) short vT[128 * 136];       // 34816 B (XOR bits 4-6, pitch 272)
    __shared__ __align__(16) short poolA[4][16 * 128];  // 16384 B: Q staging, then per-wave f/k
    __shared__ __align__(16) short poolB[16 * 136];     //  4352 B: x_lds, then attnW
    __shared__ __align__(16) float logit_s[16 * LPITCH];//  6400 B
    short* q_lds = poolA[0];
    short* x_lds = poolB;
    short* attnW = poolB;

    int t = threadIdx.x, lane = t & 63, wid = t >> 6;
    int r16 = lane & 15, hi = lane >> 4;

    int bx = blockIdx.x;                 // 4 * 196
    int b  = bx / 196;
    int rr = bx % 196;
    int th = rr / 14, tw = rr % 14;
    int ih0 = min(max(th*4 - 3, 0), HW - 10);
    int iw0 = min(max(tw*4 - 3, 0), HW - 10);

    // ---- stage x patch: 3ch x 21x21 f32 -> bf16 LDS, zero-filled at borders ----
    {
        int ihA = 2*ih0 - 1, iwA = 2*iw0 - 1;
        #pragma unroll
        for (int it = 0; it < 6; ++it) {
            int i = t + 256*it;            // 0..1535, 1512 used
            if (i < 1512) {
                int ci = i / XCH, r = i % XCH;
                int row = r / XPITCH, col = r % XPITCH;
                int ih = ihA + row, iw = iwA + col;
                float xv = 0.f;
                if (col < 21 && ih >= 0 && ih < 112 && iw >= 0 && iw < 112)
                    xv = x[((size_t)(b*3 + ci)*112 + ih)*112 + iw];
                x_lds[i] = bfbits(xv);
            }
        }
    }

    // zero vT LOGICAL units 14,15 (n in [112,128) — never written, read by PV)
    for (int i = t; i < 1024; i += 256) {
        int c = i >> 3, j = i & 7;
        int hsw = (c >> 3) & 7;
        int unit = (14 + (j >> 2)) ^ hsw;
        *(unsigned*)((char*)vT + c*VPITCH + (unit << 4) + (j & 3)*4) = 0u;
    }

    // ---- hoisted per-lane constants ----
    int  offb[8];
    bool vmask[8];
    #pragma unroll
    for (int j = 0; j < 8; ++j) {
        int k = hi*8 + j;
        int ci = k/9, r9 = k%9, kh = r9/3, kw_ = r9%3;
        offb[j]  = ci*XCH + kh*XPITCH + kw_;
        vmask[j] = (k < 27);
    }
    float qbias[2];
    #pragma unroll
    for (int i = 0; i < 2; ++i) qbias[i] = qb[(wid*2 + i)*16 + r16];

    __syncthreads();   // B1: x_lds ready

    // ---- Q phase: conv (cross-wave split, 2 ct/wave) + GEMM -> qa registers ----
    short8 qa[4];
    {
        int cout0 = (wid*2 + 0)*16 + r16;
        int cout1 = (wid*2 + 1)*16 + r16;
        short8 cbw0 = *(const short8*)((const short*)wcf + (hi*128 + cout0)*8);
        short8 cbw1 = *(const short8*)((const short*)wcf + (hi*128 + cout1)*8);
        float cbias0 = cb[cout0], cbias1 = cb[cout1];

        int ph = th*4 + (r16 >> 2), pw = tw*4 + (r16 & 3);
        int hl = ph - ih0, wl = pw - iw0;
        int pb = hl*(2*XPITCH) + wl*2;
        short8 af;
        #pragma unroll
        for (int j = 0; j < 8; ++j)
            af[j] = vmask[j] ? x_lds[offb[j] + pb] : (short)0;
        #pragma unroll
        for (int ctl = 0; ctl < 2; ++ctl) {
            int cout   = ctl ? cout1  : cout0;
            short8 bw  = ctl ? cbw1   : cbw0;
            float bias = ctl ? cbias1 : cbias0;
            f32x4 acc = {0.f, 0.f, 0.f, 0.f};
            acc = __builtin_amdgcn_mfma_f32_16x16x32_bf16(af, bw, acc, 0, 0, 0);
            int colblk = cout >> 3, inb = (cout & 7)*2;
            #pragma unroll
            for (int rg = 0; rg < 4; ++rg) {
                int px = hi*4 + rg;
                *(short*)((char*)q_lds + px*256 + ((colblk ^ px) << 4) + inb)
                    = bfbits(fmaxf(acc[rg] + bias, 0.f));
            }
        }
        __syncthreads();   // B2: f(center) ready in q_lds

        short8 fa[4];
        #pragma unroll
        for (int kk = 0; kk < 4; ++kk)
            fa[kk] = *(const short8*)((char*)q_lds + r16*256 + (((kk*4 + hi) ^ r16) << 4));

        __syncthreads();   // B3: all fa reads done; q_lds writable

        #pragma unroll
        for (int i = 0; i < 2; ++i) {
            int ct = wid*2 + i;
            const short* wb = (const short*)wqkv + hi*1024 + r16*8 + ct*128;
            f32x4 acc = {0.f, 0.f, 0.f, 0.f};
            acc = __builtin_amdgcn_mfma_f32_16x16x32_bf16(fa[0], *(const short8*)(wb),         acc, 0, 0, 0);
            acc = __builtin_amdgcn_mfma_f32_16x16x32_bf16(fa[1], *(const short8*)(wb +  4096), acc, 0, 0, 0);
            acc = __builtin_amdgcn_mfma_f32_16x16x32_bf16(fa[2], *(const short8*)(wb +  8192), acc, 0, 0, 0);
            acc = __builtin_amdgcn_mfma_f32_16x16x32_bf16(fa[3], *(const short8*)(wb + 12288), acc, 0, 0, 0);
            int c = ct*16 + r16;
            float bb = qbias[i];
            #pragma unroll
            for (int rg = 0; rg < 4; ++rg) {
                int px = hi*4 + rg;
                *(short*)((char*)q_lds + px*256 + (((c >> 3) ^ px) << 4) + (c & 7)*2)
                    = bfbits(acc[rg] + bb);
            }
        }
        __syncthreads();   // B4: q ready

        #pragma unroll
        for (int kk = 0; kk < 4; ++kk)
            qa[kk] = *(const short8*)((char*)q_lds + r16*256 + (((kk*4 + hi) ^ r16) << 4));
        __syncthreads();   // B5: qa loaded by all; poolA[0] free for wave 0
    }

    // ---- phase 4: per-wave chunk processing, NO barriers ----
    // wave w owns chunks {w, w+4} (wave 3: {3}); private buffer poolA[wid]: f then k.
    {
        short* myb = poolA[wid];

        short8 cbw8[8];
        float  cbias8[8], kbias8[8], vbias8[8];
        #pragma unroll
        for (int ct = 0; ct < 8; ++ct) {
            int c = ct*16 + r16;
            cbw8[ct]   = *(const short8*)((const short*)wcf + (hi*128 + c)*8);
            cbias8[ct] = cb[c];
            kbias8[ct] = kb[c];
            vbias8[ct] = vb[c];
        }

        #pragma unroll
        for (int j = 0; j < 2; ++j) {
            int cc = wid + 4*j;
            if (cc < 7) {
                int nc = min(cc*16 + r16, 99);
                int hl = nc/10, wl = nc - 10*hl;
                int pb = hl*(2*XPITCH) + wl*2;
                short8 af;
                #pragma unroll
                for (int j2 = 0; j2 < 8; ++j2)
                    af[j2] = vmask[j2] ? x_lds[offb[j2] + pb] : (short)0;

                // conv: all 8 col-tiles -> f in private buffer
                #pragma unroll
                for (int ct = 0; ct < 8; ++ct) {
                    f32x4 acc = {0.f, 0.f, 0.f, 0.f};
                    acc = __builtin_amdgcn_mfma_f32_16x16x32_bf16(af, cbw8[ct], acc, 0, 0, 0);
                    int cout = ct*16 + r16;
                    int colblk = cout >> 3, inb = (cout & 7)*2;
                    #pragma unroll
                    for (int rg = 0; rg < 4; ++rg) {
                        int px = hi*4 + rg;
                        *(short*)((char*)myb + px*256 + ((colblk ^ px) << 4) + inb)
                            = bfbits(fmaxf(acc[rg] + cbias8[ct], 0.f));
                    }
                }

                // f fragments (same-wave DS ordering; compiler inserts lgkmcnt)
                short8 fa[4];
                #pragma unroll
                for (int kk = 0; kk < 4; ++kk)
                    fa[kk] = *(const short8*)((char*)myb + r16*256 + (((kk*4 + hi) ^ r16) << 4));

                // K GEMM: all 8 col-tiles -> k into SAME private buffer (fa already read;
                // same-wave DS ops are in-order -> write-after-read safe)
                #pragma unroll
                for (int ct = 0; ct < 8; ++ct) {
                    const short* wb = (const short*)wqkv + 16384 + hi*1024 + r16*8 + ct*128;
                    f32x4 acc = {0.f, 0.f, 0.f, 0.f};
                    acc = __builtin_amdgcn_mfma_f32_16x16x32_bf16(fa[0], *(const short8*)(wb),         acc, 0, 0, 0);
                    acc = __builtin_amdgcn_mfma_f32_16x16x32_bf16(fa[1], *(const short8*)(wb +  4096), acc, 0, 0, 0);
                    acc = __builtin_amdgcn_mfma_f32_16x16x32_bf16(fa[2], *(const short8*)(wb +  8192), acc, 0, 0, 0);
                    acc = __builtin_amdgcn_mfma_f32_16x16x32_bf16(fa[3], *(const short8*)(wb + 12288), acc, 0, 0, 0);
                    int c = ct*16 + r16;
                    int swz = c >> 3;
                    #pragma unroll
                    for (int rg = 0; rg < 4; ++rg) {
                        int nl = hi*4 + rg;                // n & 15
                        *(short*)((char*)myb + nl*256 + ((swz ^ nl) << 4) + (c & 7)*2)
                            = bfbits(acc[rg] + kbias8[ct]);
                    }
                }

                // V GEMM: all 8 col-tiles -> vT (rows n = cc*16.., disjoint across waves)
                #pragma unroll
                for (int ct = 0; ct < 8; ++ct) {
                    const short* wb = (const short*)wqkv + 2*16384 + hi*1024 + r16*8 + ct*128;
                    f32x4 acc = {0.f, 0.f, 0.f, 0.f};
                    acc = __builtin_amdgcn_mfma_f32_16x16x32_bf16(fa[0], *(const short8*)(wb),         acc, 0, 0, 0);
                    acc = __builtin_amdgcn_mfma_f32_16x16x32_bf16(fa[1], *(const short8*)(wb +  4096), acc, 0, 0, 0);
                    acc = __builtin_amdgcn_mfma_f32_16x16x32_bf16(fa[2], *(const short8*)(wb +  8192), acc, 0, 0, 0);
                    acc = __builtin_amdgcn_mfma_f32_16x16x32_bf16(fa[3], *(const short8*)(wb + 12288), acc, 0, 0, 0);
                    int c = ct*16 + r16;
                    float bb = vbias8[ct];
                    int n0 = cc*16 + hi*4;
                    unsigned lo  = packbf(acc[0] + bb, acc[1] + bb);
                    unsigned hi2 = packbf(acc[2] + bb, acc[3] + bb);
                    int hsw = (c >> 3) & 7;
                    int off = (2*n0) ^ (hsw << 4);
                    *(uint2*)((char*)vT + c*VPITCH + off) = make_uint2(lo, hi2);
                }

                // QK^T for this chunk (k in private buffer), logits -> logit_s
                {
                    const char* kbase = (const char*)myb + r16*256;
                    f32x4 acc = {0.f, 0.f, 0.f, 0.f};
                    #pragma unroll
                    for (int kk = 0; kk < 4; ++kk) {
                        short8 kv = *(const short8*)(kbase + (((kk*4 + hi) ^ r16) << 4));
                        acc = __builtin_amdgcn_mfma_f32_16x16x32_bf16(qa[kk], kv, acc, 0, 0, 0);
                    }
                    int col = cc*16 + r16;
                    if (col < 100) {
                        #pragma unroll
                        for (int rg = 0; rg < 4; ++rg)
                            logit_s[(hi*4 + rg)*LPITCH + col] = acc[rg];
                    }
                }
            }
        }
    }
    __syncthreads();   // B6: vT + logit_s complete; x_lds dead

    // ---- zero attnW (aliases x_lds) ----
    {
        unsigned* aw = (unsigned*)attnW;
        for (int i = t; i < 1088; i += 256) aw[i] = 0u;
    }
    __syncthreads();   // B7: attnW zeroed

    // ---- softmax per pixel (4 px per wave, lane=neighbor), scatter bf16 to attnW ----
    {
        int r7 = lane / 7, s7 = lane - 7*r7;
        bool valid = lane < 49;
        const float scale = 0.08838834764831845f;   // 128^-0.5
        #pragma unroll
        for (int px = 0; px < 4; ++px) {
            int p = wid*4 + px;
            int h = th*4 + (p >> 2), w = tw*4 + (p & 3);
            int hs = min(max(h - 3, 0), HW - 7);
            int ws = min(max(w - 3, 0), HW - 7);
            int col = (hs - ih0 + r7)*10 + (ws - iw0 + s7);
            float lg = valid ? logit_s[p*LPITCH + col] * scale : -INFINITY;
            float m = lg;
            #pragma unroll
            for (int d = 1; d < 64; d <<= 1) m = fmaxf(m, __shfl_xor(m, d));
            float e = valid ? __expf(lg - m) : 0.f;
            float s = e;
            #pragma unroll
            for (int d = 1; d < 64; d <<= 1) s += __shfl_xor(s, d);
            if (valid) {
                __hip_bfloat16 hb = __float2bfloat16(e / s);
                *(__hip_bfloat16*)((char*)attnW + p*VPITCH + 2*col) = hb;
            }
        }
    }
    __syncthreads();   // B8: attnW ready

    // ---- PV: out[16][128] = attnW x vT^T ----
    short8 pa[4];
    #pragma unroll
    for (int kk = 0; kk < 4; ++kk)
        pa[kk] = *(const short8*)((char*)attnW + r16*VPITCH + kk*64 + hi*16);

    for (int nt = wid; nt < 8; nt += 4) {
        int c   = nt*16 + r16;
        int hsw = (c >> 3) & 7;
        const char* vrow = (const char*)vT + c*VPITCH;
        f32x4 acc = {0.f, 0.f, 0.f, 0.f};
        #pragma unroll
        for (int kk = 0; kk < 4; ++kk) {
            short8 vbr = *(const short8*)(vrow + ((kk*64 + hi*16) ^ (hsw << 4)));
            acc = __builtin_amdgcn_mfma_f32_16x16x32_bf16(pa[kk], vbr, acc, 0, 0, 0);
        }
        #pragma unroll
        for (int rg = 0; rg < 4; ++rg) {
            int p = hi*4 + rg;
            int h = th*4 + (p >> 2), w = tw*4 + (p & 3);
            out[(((size_t)b*C + c)*HW + h)*HW + w] = acc[rg];
        }
    }
}

extern "C" void kernel_launch(void* const* d_in, const int* in_sizes, int n_in,
                              void* d_out, int out_size, void* d_ws, size_t ws_size,
                              hipStream_t stream) {
    const float* x      = (const float*)d_in[0];
    const float* conv_w = (const float*)d_in[1];
    const float* conv_b = (const float*)d_in[2];
    const float* q_w    = (const float*)d_in[3];
    const float* q_b    = (const float*)d_in[4];
    const float* k_w    = (const float*)d_in[5];
    const float* k_b    = (const float*)d_in[6];
    const float* v_w    = (const float*)d_in[7];
    const float* v_b    = (const float*)d_in[8];
    float* out = (float*)d_out;

    __hip_bfloat16* wqkv = (__hip_bfloat16*)d_ws;        // 3*16384
    __hip_bfloat16* wcf  = wqkv + 3 * 16384;             // 4096

    prep_kernel<<<208, 256, 0, stream>>>(conv_w, q_w, k_w, v_w, wcf, wqkv);
    fused_kernel<<<NB*196, 256, 0, stream>>>(x, wcf, conv_b, wqkv,
                                             q_b, k_b, v_b, out);
}